// Round 4
// baseline (15722.792 us; speedup 1.0000x reference)
//
#include <hip/hip_runtime.h>

#define BB 64
#define PP 196
#define EE 2048
#define LL 32
#define VV 10000
#define EMBD 512
#define DECD 512
#define ATTD 512
#define TT 31

// ---------------- setup kernels ----------------

extern "C" __global__ void k_sort(const int* __restrict__ cap_len,
                                  int* __restrict__ sort_ind,
                                  int* __restrict__ dlens) {
  int i = threadIdx.x;
  if (i >= BB) return;
  int li = cap_len[i];
  int rank = 0;
  for (int j = 0; j < BB; ++j) {
    int lj = cap_len[j];
    rank += (lj > li) || (lj == li && j < i);   // stable argsort(-lens)
  }
  sort_ind[rank] = i;
  dlens[rank] = li - 1;
}

__global__ __launch_bounds__(256) void k_mean(const float* __restrict__ enc,
                                              const int* __restrict__ sort_ind,
                                              float* __restrict__ mean_enc) {
  int b = blockIdx.x >> 3;                       // E/256 = 8 blocks per b
  int e = ((blockIdx.x & 7) << 8) + threadIdx.x;
  int sb = sort_ind[b];
  const float* base = enc + (size_t)sb * PP * EE + e;
  float s = 0.f;
#pragma unroll 4
  for (int p = 0; p < PP; ++p) s += base[(size_t)p * EE];
  mean_enc[b * EE + e] = s * (1.0f / PP);
}

__global__ __launch_bounds__(256) void k_h0c0(const float* __restrict__ mean_enc,
                                              const float* __restrict__ Whi,
                                              const float* __restrict__ bhi,
                                              const float* __restrict__ Wci,
                                              const float* __restrict__ bci,
                                              float* __restrict__ h0,
                                              float* __restrict__ c0) {
  int idx = blockIdx.x * 256 + threadIdx.x;      // 2*B*DEC = 65536
  int which = idx >> 15;
  int r = idx & 32767;
  int b = r >> 9, j = r & 511;
  const float* W = which ? Wci : Whi;
  float acc = which ? bci[j] : bhi[j];
  const float* m = mean_enc + b * EE;
#pragma unroll 4
  for (int k = 0; k < EE; ++k) acc = fmaf(m[k], W[k * DECD + j], acc);
  if (which) c0[r] = acc; else h0[r] = acc;
}

// att1 = enc[sorted] @ We + be   (M=B*P=12544, K=2048, N=512), fp32
__global__ __launch_bounds__(256) void k_att1(const float* __restrict__ enc,
                                              const int* __restrict__ sort_ind,
                                              const float* __restrict__ We,
                                              const float* __restrict__ be,
                                              float* __restrict__ att1) {
  int row0 = blockIdx.x * 8;
  int j = threadIdx.x;
  const float* ap[8];
#pragma unroll
  for (int m = 0; m < 8; ++m) {
    int row = row0 + m;
    int b = row / PP, p = row - b * PP;
    int sb = sort_ind[b];
    ap[m] = enc + ((size_t)sb * PP + p) * EE;
  }
  float acc0[8], acc1[8];
  float be0 = be[j], be1 = be[j + 256];
#pragma unroll
  for (int m = 0; m < 8; ++m) { acc0[m] = be0; acc1[m] = be1; }
#pragma unroll 2
  for (int k = 0; k < EE; ++k) {
    float w0 = We[k * ATTD + j];
    float w1 = We[k * ATTD + j + 256];
#pragma unroll
    for (int m = 0; m < 8; ++m) {
      float a = ap[m][k];
      acc0[m] = fmaf(a, w0, acc0[m]);
      acc1[m] = fmaf(a, w1, acc1[m]);
    }
  }
#pragma unroll
  for (int m = 0; m < 8; ++m) {
    att1[(size_t)(row0 + m) * ATTD + j] = acc0[m];
    att1[(size_t)(row0 + m) * ATTD + j + 256] = acc1[m];
  }
}

// ---------------- per-step kernels ----------------

// hpart[sk][b][col2560] partials of h@[Wd|Wb]. Block: 64 colthreads x 4 cols x
// 4 rowgroups x 16 rows (all 64 rows in-block -> L1 absorbs weight re-reads).
// grid = 10 colblocks x 4 splitK, kr=128.
__global__ __launch_bounds__(256) void k_hproj(const float* __restrict__ h_in,
                                               const float* __restrict__ Wd,
                                               const float* __restrict__ Wb,
                                               float* __restrict__ hpart) {
  int cb = blockIdx.x % 10;
  int sk = blockIdx.x / 10;                      // 0..3
  int ct = threadIdx.x & 63;
  int rg = threadIdx.x >> 6;                     // 0..3
  int col = cb * 256 + ct * 4;
  int m0 = rg * 16;
  int k0 = sk * 128;
  const float* W;
  int ldw;
  if (col < ATTD) { W = Wd + (size_t)k0 * ATTD + col; ldw = ATTD; }
  else            { W = Wb + (size_t)k0 * EE + (col - ATTD); ldw = EE; }
  const float* hp = h_in + m0 * DECD + k0;
  float acc[16][4];
#pragma unroll
  for (int i = 0; i < 16; ++i)
#pragma unroll
    for (int c = 0; c < 4; ++c) acc[i][c] = 0.f;
#pragma unroll 2
  for (int kk = 0; kk < 128; ++kk) {
    float4 w = *(const float4*)(W + (size_t)kk * ldw);
#pragma unroll
    for (int i = 0; i < 16; ++i) {
      float xv = hp[i * DECD + kk];
      acc[i][0] = fmaf(xv, w.x, acc[i][0]);
      acc[i][1] = fmaf(xv, w.y, acc[i][1]);
      acc[i][2] = fmaf(xv, w.z, acc[i][2]);
      acc[i][3] = fmaf(xv, w.w, acc[i][3]);
    }
  }
  float* out = hpart + (size_t)sk * (BB * 2560) + m0 * 2560 + col;
#pragma unroll
  for (int i = 0; i < 16; ++i)
    *(float4*)(out + i * 2560) = make_float4(acc[i][0], acc[i][1], acc[i][2], acc[i][3]);
}

// reduce hpart -> att2 (+bd) / gateLin (+bb); copy emb_t and h into xfull.
__global__ __launch_bounds__(256) void k_hred(const float* __restrict__ hpart,
                                              const float* __restrict__ bd,
                                              const float* __restrict__ bb,
                                              const float* __restrict__ emb,
                                              const int* __restrict__ caps,
                                              const int* __restrict__ sort_ind,
                                              const float* __restrict__ h_in,
                                              float* __restrict__ att2,
                                              float* __restrict__ gateLin,
                                              float* __restrict__ xfull,
                                              int t) {
  int idx = blockIdx.x * 256 + threadIdx.x;      // 64*2560 + 64*1024 = 229376
  if (idx < BB * 2560) {
    int b = idx / 2560, c = idx % 2560;
    float s = 0.f;
#pragma unroll
    for (int sk = 0; sk < 4; ++sk) s += hpart[(size_t)sk * (BB * 2560) + idx];
    if (c < ATTD) att2[b * ATTD + c] = s + bd[c];
    else gateLin[b * EE + (c - ATTD)] = s + bb[c - ATTD];
  } else {
    int cidx = idx - BB * 2560;                  // 0..65535
    int b = cidx >> 10, k = cidx & 1023;
    if (k < EMBD) {
      int cap = caps[sort_ind[b] * LL + t];
      xfull[b * 3072 + k] = emb[(size_t)cap * EMBD + k];
    } else {
      xfull[b * 3072 + 2560 + (k - EMBD)] = h_in[b * DECD + (k - EMBD)];
    }
  }
}

// e[b,p] = relu(att1[b,p,:] + att2[b,:]) . Wf + bf   (one wave per (b,p), float4)
__global__ __launch_bounds__(256) void k_e(const float* __restrict__ att1,
                                           const float* __restrict__ att2,
                                           const float* __restrict__ Wf,
                                           const float* __restrict__ bf,
                                           float* __restrict__ e) {
  int wave = (blockIdx.x * 256 + threadIdx.x) >> 6;
  int lane = threadIdx.x & 63;
  int b = wave / PP, p = wave - b * PP;
  const float4* a1 = (const float4*)(att1 + (size_t)(b * PP + p) * ATTD);
  const float4* a2 = (const float4*)(att2 + b * ATTD);
  const float4* wf = (const float4*)Wf;
  float acc = 0.f;
#pragma unroll
  for (int r = 0; r < 2; ++r) {
    int k4 = lane + r * 64;
    float4 x = a1[k4], y = a2[k4], f = wf[k4];
    acc = fmaf(fmaxf(x.x + y.x, 0.f), f.x, acc);
    acc = fmaf(fmaxf(x.y + y.y, 0.f), f.y, acc);
    acc = fmaf(fmaxf(x.z + y.z, 0.f), f.z, acc);
    acc = fmaf(fmaxf(x.w + y.w, 0.f), f.w, acc);
  }
#pragma unroll
  for (int off = 32; off; off >>= 1) acc += __shfl_xor(acc, off);
  if (lane == 0) e[b * PP + p] = acc + bf[0];
}

// softmax over p, awe = sum_p alpha*enc (float4), gate, write xfull[:,512:2560]
// grid (b,chunk): 128 blocks; chunk covers 1024 of E=2048 (float4/thread)
__global__ __launch_bounds__(256) void k_awe(const float* __restrict__ e,
                                             const float* __restrict__ enc,
                                             const int* __restrict__ sort_ind,
                                             const float* __restrict__ gateLin,
                                             const int* __restrict__ dlens,
                                             float* __restrict__ xfull,
                                             float* __restrict__ alphas_out,
                                             int t) {
  int b = blockIdx.x >> 1, c = blockIdx.x & 1;
  int tid = threadIdx.x;
  __shared__ float sa[PP];
  float ev = 0.f;
  if (tid < PP) { ev = e[b * PP + tid]; sa[tid] = ev; }
  __syncthreads();
  float m = -1e30f;
  for (int p = 0; p < PP; ++p) m = fmaxf(m, sa[p]);
  __syncthreads();
  if (tid < PP) sa[tid] = expf(ev - m);
  __syncthreads();
  float s = 0.f;
  for (int p = 0; p < PP; ++p) s += sa[p];
  float inv = 1.0f / s;

  int e0 = (c << 10) + tid * 4;
  int sb = sort_ind[b];
  const float* base = enc + (size_t)sb * PP * EE + e0;
  float ax = 0.f, ay = 0.f, az = 0.f, aw = 0.f;
#pragma unroll 4
  for (int p = 0; p < PP; ++p) {
    float a = sa[p];
    float4 v = *(const float4*)(base + (size_t)p * EE);
    ax = fmaf(a, v.x, ax);
    ay = fmaf(a, v.y, ay);
    az = fmaf(a, v.z, az);
    aw = fmaf(a, v.w, aw);
  }
  float4 gl = *(const float4*)(gateLin + b * EE + e0);
  float gx = 1.f / (1.f + expf(-gl.x));
  float gy = 1.f / (1.f + expf(-gl.y));
  float gz = 1.f / (1.f + expf(-gl.z));
  float gw = 1.f / (1.f + expf(-gl.w));
  *(float4*)(xfull + b * 3072 + EMBD + e0) =
      make_float4(ax * inv * gx, ay * inv * gy, az * inv * gz, aw * inv * gw);
  if (c == 0 && tid < PP) {
    float msk = (t < dlens[b]) ? 1.f : 0.f;
    alphas_out[((size_t)b * TT + t) * PP + tid] = sa[tid] * inv * msk;
  }
}

// gpart[sk][b][col2048]: xfull(64x3072) @ [Wih;Whh]. Block: 256 cols x 64 rows
// (4 rowgroups x 16). grid = 8 colblocks x 6 splitK, kr=512 (chunk 5 = Whh).
__global__ __launch_bounds__(256) void k_gates(const float* __restrict__ xfull,
                                               const float* __restrict__ Wih,
                                               const float* __restrict__ Whh,
                                               float* __restrict__ gpart) {
  int cb = blockIdx.x & 7;
  int sk = blockIdx.x >> 3;                      // 0..5
  int ct = threadIdx.x & 63;
  int rg = threadIdx.x >> 6;
  int col = cb * 256 + ct * 4;
  int m0 = rg * 16;
  const float* W = (sk < 5) ? (Wih + (size_t)(sk * 512) * EE + col)
                            : (Whh + col);
  const float* xb = xfull + m0 * 3072 + sk * 512;
  float acc[16][4];
#pragma unroll
  for (int i = 0; i < 16; ++i)
#pragma unroll
    for (int c = 0; c < 4; ++c) acc[i][c] = 0.f;
#pragma unroll 2
  for (int kk = 0; kk < 512; ++kk) {
    float4 w = *(const float4*)(W + (size_t)kk * EE);
#pragma unroll
    for (int i = 0; i < 16; ++i) {
      float xv = xb[i * 3072 + kk];
      acc[i][0] = fmaf(xv, w.x, acc[i][0]);
      acc[i][1] = fmaf(xv, w.y, acc[i][1]);
      acc[i][2] = fmaf(xv, w.z, acc[i][2]);
      acc[i][3] = fmaf(xv, w.w, acc[i][3]);
    }
  }
  float* out = gpart + (size_t)sk * (BB * EE) + m0 * EE + col;
#pragma unroll
  for (int i = 0; i < 16; ++i)
    *(float4*)(out + i * EE) = make_float4(acc[i][0], acc[i][1], acc[i][2], acc[i][3]);
}

__global__ __launch_bounds__(256) void k_cell(const float* __restrict__ gpart,
                                              const float* __restrict__ bih,
                                              const float* __restrict__ bhh,
                                              const float* __restrict__ c_in,
                                              float* __restrict__ h_out,
                                              float* __restrict__ c_out) {
  int idx = blockIdx.x * 256 + threadIdx.x;      // B*DEC = 32768
  int b = idx >> 9, j = idx & 511;
  float gi = bih[j] + bhh[j];
  float gf = bih[j + 512] + bhh[j + 512];
  float gg = bih[j + 1024] + bhh[j + 1024];
  float go = bih[j + 1536] + bhh[j + 1536];
#pragma unroll
  for (int s = 0; s < 6; ++s) {
    const float* gp = gpart + (size_t)s * (BB * EE) + b * EE;
    gi += gp[j];
    gf += gp[j + 512];
    gg += gp[j + 1024];
    go += gp[j + 1536];
  }
  float ig = 1.f / (1.f + expf(-gi));
  float fg = 1.f / (1.f + expf(-gf));
  float gt = tanhf(gg);
  float og = 1.f / (1.f + expf(-go));
  float cn = fg * c_in[idx] + ig * gt;
  float hn = og * tanhf(cn);
  h_out[idx] = hn;   // masked rows: preds output is zeroed by mask anyway
  c_out[idx] = cn;
}

// preds = (h_out @ Wfc + bfc) * mask. Block 512 thr: 64 ct x 4 cols, 8 rg x 8
// rows (all 64 rows in-block). grid = 40 colblocks, direct K=512.
__global__ __launch_bounds__(512) void k_preds(const float* __restrict__ hn,
                                               const float* __restrict__ Wfc,
                                               const float* __restrict__ bfc,
                                               const int* __restrict__ dlens,
                                               float* __restrict__ out,
                                               int t) {
  int ct = threadIdx.x & 63;
  int rg = threadIdx.x >> 6;                     // 0..7
  int col = blockIdx.x * 256 + ct * 4;
  if (col >= VV) return;
  int m0 = rg * 8;
  const float* hp = hn + m0 * DECD;
  float acc[8][4];
  float4 bv = *(const float4*)(bfc + col);
#pragma unroll
  for (int i = 0; i < 8; ++i) {
    acc[i][0] = bv.x; acc[i][1] = bv.y; acc[i][2] = bv.z; acc[i][3] = bv.w;
  }
#pragma unroll 2
  for (int k = 0; k < DECD; ++k) {
    float4 w = *(const float4*)(Wfc + (size_t)k * VV + col);
#pragma unroll
    for (int i = 0; i < 8; ++i) {
      float xv = hp[i * DECD + k];
      acc[i][0] = fmaf(xv, w.x, acc[i][0]);
      acc[i][1] = fmaf(xv, w.y, acc[i][1]);
      acc[i][2] = fmaf(xv, w.z, acc[i][2]);
      acc[i][3] = fmaf(xv, w.w, acc[i][3]);
    }
  }
#pragma unroll
  for (int i = 0; i < 8; ++i) {
    int b = m0 + i;
    float msk = (t < dlens[b]) ? 1.f : 0.f;
    *(float4*)(out + ((size_t)b * TT + t) * VV + col) =
        make_float4(acc[i][0] * msk, acc[i][1] * msk, acc[i][2] * msk, acc[i][3] * msk);
  }
}

// ---------------- launch ----------------

extern "C" void kernel_launch(void* const* d_in, const int* in_sizes, int n_in,
                              void* d_out, int out_size, void* d_ws, size_t ws_size,
                              hipStream_t stream) {
  const float* enc  = (const float*)d_in[0];
  const int*   caps = (const int*)d_in[1];
  const int*   clen = (const int*)d_in[2];
  const float* emb  = (const float*)d_in[3];
  const float* We   = (const float*)d_in[4];
  const float* be   = (const float*)d_in[5];
  const float* Wd   = (const float*)d_in[6];
  const float* bd   = (const float*)d_in[7];
  const float* Wf   = (const float*)d_in[8];
  const float* bf   = (const float*)d_in[9];
  const float* Wih  = (const float*)d_in[10];
  const float* bih  = (const float*)d_in[11];
  const float* Whh  = (const float*)d_in[12];
  const float* bhh  = (const float*)d_in[13];
  const float* Wb   = (const float*)d_in[14];
  const float* bb   = (const float*)d_in[15];
  const float* Whi  = (const float*)d_in[16];
  const float* bhi  = (const float*)d_in[17];
  const float* Wci  = (const float*)d_in[18];
  const float* bci  = (const float*)d_in[19];
  const float* Wfc  = (const float*)d_in[20];
  const float* bfc  = (const float*)d_in[21];

  // ws layout (floats). Total 7,700,608 fl = 30,802,432 B (< proven 29.41MB? no:
  // previous high-water was 29,410,816 B; this is 30.8MB -- see spart aliasing,
  // every buffer below is within [0, 7,700,608).)
  float* ws = (float*)d_ws;
  int* sort_ind  = (int*)ws;                     // 64
  int* dlens     = (int*)(ws + 64);              // 64
  float* hbuf0   = ws + 128;                     // 32768
  float* hbuf1   = ws + 32896;                   // 32768
  float* cbuf0   = ws + 65664;                   // 32768
  float* cbuf1   = ws + 98432;                   // 32768
  float* att2    = ws + 131200;                  // 32768
  float* gateLin = ws + 163968;                  // 131072
  float* xfull   = ws + 295040;                  // 196608
  float* spart   = ws + 491648;                  // 786432 shared scratch:
  float* mean_enc = spart;                       //   setup only (131072)
  float* hpart    = spart;                       //   stage 1-2 (4*64*2560=655360)
  float* ebuf     = spart;                       //   stage 3-4 (12544)
  float* gpart    = spart;                       //   stage 5-6 (6*64*2048=786432)
  float* att1    = ws + 1278080;                 // 6422528; end = 7,700,608
  float* preds_out  = (float*)d_out;
  float* alphas_out = preds_out + (size_t)BB * TT * VV;

  hipLaunchKernelGGL(k_sort, dim3(1), dim3(64), 0, stream, clen, sort_ind, dlens);
  hipLaunchKernelGGL(k_mean, dim3(512), dim3(256), 0, stream, enc, sort_ind, mean_enc);
  hipLaunchKernelGGL(k_h0c0, dim3(256), dim3(256), 0, stream, mean_enc, Whi, bhi, Wci, bci,
                     hbuf0, cbuf0);
  hipLaunchKernelGGL(k_att1, dim3(1568), dim3(256), 0, stream, enc, sort_ind, We, be, att1);

  float* hb[2] = {hbuf0, hbuf1};
  float* cb[2] = {cbuf0, cbuf1};
  for (int t = 0; t < TT; ++t) {
    const float* h_in = hb[t & 1];
    const float* c_in = cb[t & 1];
    float* h_out = hb[(t + 1) & 1];
    float* c_out = cb[(t + 1) & 1];
    hipLaunchKernelGGL(k_hproj, dim3(40), dim3(256), 0, stream, h_in, Wd, Wb, hpart);
    hipLaunchKernelGGL(k_hred, dim3(896), dim3(256), 0, stream,
                       hpart, bd, bb, emb, caps, sort_ind, h_in, att2, gateLin, xfull, t);
    hipLaunchKernelGGL(k_e, dim3(3136), dim3(256), 0, stream, att1, att2, Wf, bf, ebuf);
    hipLaunchKernelGGL(k_awe, dim3(128), dim3(256), 0, stream,
                       ebuf, enc, sort_ind, gateLin, dlens, xfull, alphas_out, t);
    hipLaunchKernelGGL(k_gates, dim3(48), dim3(256), 0, stream, xfull, Wih, Whh, gpart);
    hipLaunchKernelGGL(k_cell, dim3(128), dim3(256), 0, stream,
                       gpart, bih, bhh, c_in, h_out, c_out);
    hipLaunchKernelGGL(k_preds, dim3(40), dim3(512), 0, stream,
                       h_out, Wfc, bfc, dlens, preds_out, t);
  }
}

// Round 5
// 8634.176 us; speedup vs baseline: 1.8210x; 1.8210x over previous
//
#include <hip/hip_runtime.h>

#define BB 64
#define PP 196
#define EE 2048
#define LL 32
#define VV 10000
#define EMBD 512
#define DECD 512
#define ATTD 512
#define TT 31

#define FMA4(av, wv, A) {A[0]=fmaf((av),(wv).x,A[0]);A[1]=fmaf((av),(wv).y,A[1]);A[2]=fmaf((av),(wv).z,A[2]);A[3]=fmaf((av),(wv).w,A[3]);}

// ---------------- setup kernels ----------------

extern "C" __global__ void k_sort(const int* __restrict__ cap_len,
                                  int* __restrict__ sort_ind,
                                  int* __restrict__ dlens) {
  int i = threadIdx.x;
  if (i >= BB) return;
  int li = cap_len[i];
  int rank = 0;
  for (int j = 0; j < BB; ++j) {
    int lj = cap_len[j];
    rank += (lj > li) || (lj == li && j < i);   // stable argsort(-lens)
  }
  sort_ind[rank] = i;
  dlens[rank] = li - 1;
}

__global__ __launch_bounds__(256) void k_mean(const float* __restrict__ enc,
                                              const int* __restrict__ sort_ind,
                                              float* __restrict__ mean_enc) {
  int b = blockIdx.x >> 3;
  int e = ((blockIdx.x & 7) << 8) + threadIdx.x;
  int sb = sort_ind[b];
  const float* base = enc + (size_t)sb * PP * EE + e;
  float s = 0.f;
#pragma unroll 4
  for (int p = 0; p < PP; ++p) s += base[(size_t)p * EE];
  mean_enc[b * EE + e] = s * (1.0f / PP);
}

// h0 = mean_enc@Whi+bhi ; c0 = mean_enc@Wci+bci  (fused, float4 both operands)
// 8192 threads = 64 b x 128 colquads -> 32 blocks
__global__ __launch_bounds__(256) void k_h0c0(const float* __restrict__ mean_enc,
                                              const float* __restrict__ Whi,
                                              const float* __restrict__ bhi,
                                              const float* __restrict__ Wci,
                                              const float* __restrict__ bci,
                                              float* __restrict__ h0,
                                              float* __restrict__ c0) {
  int idx = blockIdx.x * 256 + threadIdx.x;      // 64*128 = 8192
  int b = idx >> 7, col = (idx & 127) * 4;
  const float* m = mean_enc + b * EE;
  float ah[4], ac[4];
  float4 bh = *(const float4*)(bhi + col);
  float4 bc = *(const float4*)(bci + col);
  ah[0]=bh.x; ah[1]=bh.y; ah[2]=bh.z; ah[3]=bh.w;
  ac[0]=bc.x; ac[1]=bc.y; ac[2]=bc.z; ac[3]=bc.w;
#pragma unroll 2
  for (int k = 0; k < EE; k += 4) {
    float4 mv = *(const float4*)(m + k);
    float4 wh0 = *(const float4*)(Whi + (size_t)(k+0)*DECD + col);
    float4 wh1 = *(const float4*)(Whi + (size_t)(k+1)*DECD + col);
    float4 wh2 = *(const float4*)(Whi + (size_t)(k+2)*DECD + col);
    float4 wh3 = *(const float4*)(Whi + (size_t)(k+3)*DECD + col);
    FMA4(mv.x, wh0, ah); FMA4(mv.y, wh1, ah); FMA4(mv.z, wh2, ah); FMA4(mv.w, wh3, ah);
    float4 wc0 = *(const float4*)(Wci + (size_t)(k+0)*DECD + col);
    float4 wc1 = *(const float4*)(Wci + (size_t)(k+1)*DECD + col);
    float4 wc2 = *(const float4*)(Wci + (size_t)(k+2)*DECD + col);
    float4 wc3 = *(const float4*)(Wci + (size_t)(k+3)*DECD + col);
    FMA4(mv.x, wc0, ac); FMA4(mv.y, wc1, ac); FMA4(mv.z, wc2, ac); FMA4(mv.w, wc3, ac);
  }
  *(float4*)(h0 + b * DECD + col) = make_float4(ah[0], ah[1], ah[2], ah[3]);
  *(float4*)(c0 + b * DECD + col) = make_float4(ac[0], ac[1], ac[2], ac[3]);
}

// att1 = enc[sorted] @ We + be  (M=12544, K=2048, N=512)
// 784 blocks = 392 rowblocks(32r) x 2 colblocks(256c); thread 8r x 4c.
__global__ __launch_bounds__(256) void k_att1(const float* __restrict__ enc,
                                              const int* __restrict__ sort_ind,
                                              const float* __restrict__ We,
                                              const float* __restrict__ be,
                                              float* __restrict__ att1) {
  int rb = blockIdx.x >> 1;
  int cbk = blockIdx.x & 1;
  int ct = threadIdx.x & 63;
  int rg = threadIdx.x >> 6;
  int col = cbk * 256 + ct * 4;
  int row0 = rb * 32 + rg * 8;
  const float* ap[8];
#pragma unroll
  for (int i = 0; i < 8; ++i) {
    int row = row0 + i;
    int b = row / PP, p = row - b * PP;
    ap[i] = enc + ((size_t)sort_ind[b] * PP + p) * EE;
  }
  float acc[8][4];
  float4 bv = *(const float4*)(be + col);
#pragma unroll
  for (int i = 0; i < 8; ++i) { acc[i][0]=bv.x; acc[i][1]=bv.y; acc[i][2]=bv.z; acc[i][3]=bv.w; }
#pragma unroll 2
  for (int k = 0; k < EE; k += 4) {
    float4 w0 = *(const float4*)(We + (size_t)(k+0)*ATTD + col);
    float4 w1 = *(const float4*)(We + (size_t)(k+1)*ATTD + col);
    float4 w2 = *(const float4*)(We + (size_t)(k+2)*ATTD + col);
    float4 w3 = *(const float4*)(We + (size_t)(k+3)*ATTD + col);
#pragma unroll
    for (int i = 0; i < 8; ++i) {
      float4 a = *(const float4*)(ap[i] + k);
      FMA4(a.x, w0, acc[i]); FMA4(a.y, w1, acc[i]);
      FMA4(a.z, w2, acc[i]); FMA4(a.w, w3, acc[i]);
    }
  }
#pragma unroll
  for (int i = 0; i < 8; ++i)
    *(float4*)(att1 + (size_t)(row0 + i) * ATTD + col) =
        make_float4(acc[i][0], acc[i][1], acc[i][2], acc[i][3]);
}

// ---------------- per-step kernels ----------------

// hpart[sk][row][col2560] partials of h@[Wd|Wb]. 160 blocks = 10cb x 4rb x 4sk.
// thread 4r x 4c, float4 both operands.
__global__ __launch_bounds__(256) void k_hproj(const float* __restrict__ h_in,
                                               const float* __restrict__ Wd,
                                               const float* __restrict__ Wb,
                                               float* __restrict__ hpart) {
  int cb = blockIdx.x % 10;
  int rb = (blockIdx.x / 10) & 3;
  int sk = blockIdx.x / 40;                      // 0..3, K-chunk 128
  int ct = threadIdx.x & 63;
  int rg = threadIdx.x >> 6;
  int col = cb * 256 + ct * 4;
  int row0 = rb * 16 + rg * 4;
  int k0 = sk * 128;
  const float* W;
  int ldw;
  if (col < ATTD) { W = Wd + (size_t)k0 * ATTD + col; ldw = ATTD; }
  else            { W = Wb + (size_t)k0 * EE + (col - ATTD); ldw = EE; }
  const float* hp = h_in + row0 * DECD + k0;
  float acc[4][4];
#pragma unroll
  for (int i = 0; i < 4; ++i)
#pragma unroll
    for (int c = 0; c < 4; ++c) acc[i][c] = 0.f;
#pragma unroll 2
  for (int k = 0; k < 128; k += 4) {
    float4 w0 = *(const float4*)(W + (size_t)(k+0)*ldw);
    float4 w1 = *(const float4*)(W + (size_t)(k+1)*ldw);
    float4 w2 = *(const float4*)(W + (size_t)(k+2)*ldw);
    float4 w3 = *(const float4*)(W + (size_t)(k+3)*ldw);
#pragma unroll
    for (int i = 0; i < 4; ++i) {
      float4 a = *(const float4*)(hp + i * DECD + k);
      FMA4(a.x, w0, acc[i]); FMA4(a.y, w1, acc[i]);
      FMA4(a.z, w2, acc[i]); FMA4(a.w, w3, acc[i]);
    }
  }
  float* out = hpart + (size_t)sk * (BB * 2560) + row0 * 2560 + col;
#pragma unroll
  for (int i = 0; i < 4; ++i)
    *(float4*)(out + i * 2560) = make_float4(acc[i][0], acc[i][1], acc[i][2], acc[i][3]);
}

// reduce hpart -> att2 (+bd) / gateLin (+bb); copy emb_t and h into xfull.
__global__ __launch_bounds__(256) void k_hred(const float* __restrict__ hpart,
                                              const float* __restrict__ bd,
                                              const float* __restrict__ bb,
                                              const float* __restrict__ emb,
                                              const int* __restrict__ caps,
                                              const int* __restrict__ sort_ind,
                                              const float* __restrict__ h_in,
                                              float* __restrict__ att2,
                                              float* __restrict__ gateLin,
                                              float* __restrict__ xfull,
                                              int t) {
  int idx = blockIdx.x * 256 + threadIdx.x;      // 64*2560 + 64*1024 = 229376
  if (idx < BB * 2560) {
    int b = idx / 2560, c = idx % 2560;
    float s = 0.f;
#pragma unroll
    for (int sk = 0; sk < 4; ++sk) s += hpart[(size_t)sk * (BB * 2560) + idx];
    if (c < ATTD) att2[b * ATTD + c] = s + bd[c];
    else gateLin[b * EE + (c - ATTD)] = s + bb[c - ATTD];
  } else {
    int cidx = idx - BB * 2560;
    int b = cidx >> 10, k = cidx & 1023;
    if (k < EMBD) {
      int cap = caps[sort_ind[b] * LL + t];
      xfull[b * 3072 + k] = emb[(size_t)cap * EMBD + k];
    } else {
      xfull[b * 3072 + 2560 + (k - EMBD)] = h_in[b * DECD + (k - EMBD)];
    }
  }
}

// e[b,p] = relu(att1[b,p,:] + att2[b,:]) . Wf + bf   (one wave per (b,p))
__global__ __launch_bounds__(256) void k_e(const float* __restrict__ att1,
                                           const float* __restrict__ att2,
                                           const float* __restrict__ Wf,
                                           const float* __restrict__ bf,
                                           float* __restrict__ e) {
  int wave = (blockIdx.x * 256 + threadIdx.x) >> 6;
  int lane = threadIdx.x & 63;
  int b = wave / PP, p = wave - b * PP;
  const float4* a1 = (const float4*)(att1 + (size_t)(b * PP + p) * ATTD);
  const float4* a2 = (const float4*)(att2 + b * ATTD);
  const float4* wf = (const float4*)Wf;
  float acc = 0.f;
#pragma unroll
  for (int r = 0; r < 2; ++r) {
    int k4 = lane + r * 64;
    float4 x = a1[k4], y = a2[k4], f = wf[k4];
    acc = fmaf(fmaxf(x.x + y.x, 0.f), f.x, acc);
    acc = fmaf(fmaxf(x.y + y.y, 0.f), f.y, acc);
    acc = fmaf(fmaxf(x.z + y.z, 0.f), f.z, acc);
    acc = fmaf(fmaxf(x.w + y.w, 0.f), f.w, acc);
  }
#pragma unroll
  for (int off = 32; off; off >>= 1) acc += __shfl_xor(acc, off);
  if (lane == 0) e[b * PP + p] = acc + bf[0];
}

// softmax over p, awe = sum_p alpha*enc (float4), gate, write xfull[:,512:2560]
__global__ __launch_bounds__(256) void k_awe(const float* __restrict__ e,
                                             const float* __restrict__ enc,
                                             const int* __restrict__ sort_ind,
                                             const float* __restrict__ gateLin,
                                             const int* __restrict__ dlens,
                                             float* __restrict__ xfull,
                                             float* __restrict__ alphas_out,
                                             int t) {
  int b = blockIdx.x >> 1, c = blockIdx.x & 1;
  int tid = threadIdx.x;
  __shared__ float sa[PP];
  float ev = 0.f;
  if (tid < PP) { ev = e[b * PP + tid]; sa[tid] = ev; }
  __syncthreads();
  float m = -1e30f;
  for (int p = 0; p < PP; ++p) m = fmaxf(m, sa[p]);
  __syncthreads();
  if (tid < PP) sa[tid] = expf(ev - m);
  __syncthreads();
  float s = 0.f;
  for (int p = 0; p < PP; ++p) s += sa[p];
  float inv = 1.0f / s;

  int e0 = (c << 10) + tid * 4;
  int sb = sort_ind[b];
  const float* base = enc + (size_t)sb * PP * EE + e0;
  float ax = 0.f, ay = 0.f, az = 0.f, aw = 0.f;
#pragma unroll 4
  for (int p = 0; p < PP; ++p) {
    float a = sa[p];
    float4 v = *(const float4*)(base + (size_t)p * EE);
    ax = fmaf(a, v.x, ax);
    ay = fmaf(a, v.y, ay);
    az = fmaf(a, v.z, az);
    aw = fmaf(a, v.w, aw);
  }
  float4 gl = *(const float4*)(gateLin + b * EE + e0);
  float gx = 1.f / (1.f + expf(-gl.x));
  float gy = 1.f / (1.f + expf(-gl.y));
  float gz = 1.f / (1.f + expf(-gl.z));
  float gw = 1.f / (1.f + expf(-gl.w));
  *(float4*)(xfull + b * 3072 + EMBD + e0) =
      make_float4(ax * inv * gx, ay * inv * gy, az * inv * gz, aw * inv * gw);
  if (c == 0 && tid < PP) {
    float msk = (t < dlens[b]) ? 1.f : 0.f;
    alphas_out[((size_t)b * TT + t) * PP + tid] = sa[tid] * inv * msk;
  }
}

// gpart[sk][row][col2048]: xfull(64x3072) @ [Wih;Whh]. 192 blocks = 8cb x 4rb x 6sk.
// thread 4r x 4c; sk 0..4 = Wih k-chunks of 512, sk 5 = Whh.
__global__ __launch_bounds__(256) void k_gates(const float* __restrict__ xfull,
                                               const float* __restrict__ Wih,
                                               const float* __restrict__ Whh,
                                               float* __restrict__ gpart) {
  int cb = blockIdx.x & 7;
  int rb = (blockIdx.x >> 3) & 3;
  int sk = blockIdx.x >> 5;                      // 0..5
  int ct = threadIdx.x & 63;
  int rg = threadIdx.x >> 6;
  int col = cb * 256 + ct * 4;
  int row0 = rb * 16 + rg * 4;
  const float* W = (sk < 5) ? (Wih + (size_t)(sk * 512) * EE + col) : (Whh + col);
  const float* xb = xfull + row0 * 3072 + (sk < 5 ? sk * 512 : 2560);
  float acc[4][4];
#pragma unroll
  for (int i = 0; i < 4; ++i)
#pragma unroll
    for (int c = 0; c < 4; ++c) acc[i][c] = 0.f;
#pragma unroll 2
  for (int k = 0; k < 512; k += 4) {
    float4 w0 = *(const float4*)(W + (size_t)(k+0)*EE);
    float4 w1 = *(const float4*)(W + (size_t)(k+1)*EE);
    float4 w2 = *(const float4*)(W + (size_t)(k+2)*EE);
    float4 w3 = *(const float4*)(W + (size_t)(k+3)*EE);
#pragma unroll
    for (int i = 0; i < 4; ++i) {
      float4 a = *(const float4*)(xb + i * 3072 + k);
      FMA4(a.x, w0, acc[i]); FMA4(a.y, w1, acc[i]);
      FMA4(a.z, w2, acc[i]); FMA4(a.w, w3, acc[i]);
    }
  }
  float* out = gpart + (size_t)sk * (BB * EE) + row0 * EE + col;
#pragma unroll
  for (int i = 0; i < 4; ++i)
    *(float4*)(out + i * EE) = make_float4(acc[i][0], acc[i][1], acc[i][2], acc[i][3]);
}

__global__ __launch_bounds__(256) void k_cell(const float* __restrict__ gpart,
                                              const float* __restrict__ bih,
                                              const float* __restrict__ bhh,
                                              const float* __restrict__ c_in,
                                              float* __restrict__ h_out,
                                              float* __restrict__ c_out) {
  int idx = blockIdx.x * 256 + threadIdx.x;      // B*DEC = 32768
  int b = idx >> 9, j = idx & 511;
  float gi = bih[j] + bhh[j];
  float gf = bih[j + 512] + bhh[j + 512];
  float gg = bih[j + 1024] + bhh[j + 1024];
  float go = bih[j + 1536] + bhh[j + 1536];
#pragma unroll
  for (int s = 0; s < 6; ++s) {
    const float* gp = gpart + (size_t)s * (BB * EE) + b * EE;
    gi += gp[j];
    gf += gp[j + 512];
    gg += gp[j + 1024];
    go += gp[j + 1536];
  }
  float ig = 1.f / (1.f + expf(-gi));
  float fg = 1.f / (1.f + expf(-gf));
  float gt = tanhf(gg);
  float og = 1.f / (1.f + expf(-go));
  float cn = fg * c_in[idx] + ig * gt;
  float hn = og * tanhf(cn);
  h_out[idx] = hn;   // masked rows: preds output is zeroed by mask anyway
  c_out[idx] = cn;
}

// preds = (h_out @ Wfc + bfc) * mask. 160 blocks = 40cb x 4rb; thread 4r x 4c.
__global__ __launch_bounds__(256) void k_preds(const float* __restrict__ hn,
                                               const float* __restrict__ Wfc,
                                               const float* __restrict__ bfc,
                                               const int* __restrict__ dlens,
                                               float* __restrict__ out,
                                               int t) {
  int cb = blockIdx.x % 40;
  int rb = blockIdx.x / 40;
  int ct = threadIdx.x & 63;
  int rg = threadIdx.x >> 6;
  int col = cb * 256 + ct * 4;
  if (col >= VV) return;
  int row0 = rb * 16 + rg * 4;
  const float* hp = hn + row0 * DECD;
  float acc[4][4];
  float4 bv = *(const float4*)(bfc + col);
#pragma unroll
  for (int i = 0; i < 4; ++i) { acc[i][0]=bv.x; acc[i][1]=bv.y; acc[i][2]=bv.z; acc[i][3]=bv.w; }
#pragma unroll 2
  for (int k = 0; k < DECD; k += 4) {
    float4 w0 = *(const float4*)(Wfc + (size_t)(k+0)*VV + col);
    float4 w1 = *(const float4*)(Wfc + (size_t)(k+1)*VV + col);
    float4 w2 = *(const float4*)(Wfc + (size_t)(k+2)*VV + col);
    float4 w3 = *(const float4*)(Wfc + (size_t)(k+3)*VV + col);
#pragma unroll
    for (int i = 0; i < 4; ++i) {
      float4 a = *(const float4*)(hp + i * DECD + k);
      FMA4(a.x, w0, acc[i]); FMA4(a.y, w1, acc[i]);
      FMA4(a.z, w2, acc[i]); FMA4(a.w, w3, acc[i]);
    }
  }
#pragma unroll
  for (int i = 0; i < 4; ++i) {
    int b = row0 + i;
    float msk = (t < dlens[b]) ? 1.f : 0.f;
    *(float4*)(out + ((size_t)b * TT + t) * VV + col) =
        make_float4(acc[i][0] * msk, acc[i][1] * msk, acc[i][2] * msk, acc[i][3] * msk);
  }
}

// ---------------- launch ----------------

extern "C" void kernel_launch(void* const* d_in, const int* in_sizes, int n_in,
                              void* d_out, int out_size, void* d_ws, size_t ws_size,
                              hipStream_t stream) {
  const float* enc  = (const float*)d_in[0];
  const int*   caps = (const int*)d_in[1];
  const int*   clen = (const int*)d_in[2];
  const float* emb  = (const float*)d_in[3];
  const float* We   = (const float*)d_in[4];
  const float* be   = (const float*)d_in[5];
  const float* Wd   = (const float*)d_in[6];
  const float* bd   = (const float*)d_in[7];
  const float* Wf   = (const float*)d_in[8];
  const float* bf   = (const float*)d_in[9];
  const float* Wih  = (const float*)d_in[10];
  const float* bih  = (const float*)d_in[11];
  const float* Whh  = (const float*)d_in[12];
  const float* bhh  = (const float*)d_in[13];
  const float* Wb   = (const float*)d_in[14];
  const float* bb   = (const float*)d_in[15];
  const float* Whi  = (const float*)d_in[16];
  const float* bhi  = (const float*)d_in[17];
  const float* Wci  = (const float*)d_in[18];
  const float* bci  = (const float*)d_in[19];
  const float* Wfc  = (const float*)d_in[20];
  const float* bfc  = (const float*)d_in[21];

  // ws layout (floats), total 7,700,608 fl = 30.8 MB (same as proven R4 layout)
  float* ws = (float*)d_ws;
  int* sort_ind  = (int*)ws;                     // 64
  int* dlens     = (int*)(ws + 64);              // 64
  float* hbuf0   = ws + 128;
  float* hbuf1   = ws + 32896;
  float* cbuf0   = ws + 65664;
  float* cbuf1   = ws + 98432;
  float* att2    = ws + 131200;
  float* gateLin = ws + 163968;
  float* xfull   = ws + 295040;
  float* spart   = ws + 491648;                  // 786432 shared scratch
  float* mean_enc = spart;                       //   setup (131072)
  float* hpart    = spart;                       //   4*64*2560 = 655360
  float* ebuf     = spart;                       //   12544
  float* gpart    = spart;                       //   6*64*2048 = 786432
  float* att1    = ws + 1278080;                 // 6422528
  float* preds_out  = (float*)d_out;
  float* alphas_out = preds_out + (size_t)BB * TT * VV;

  hipLaunchKernelGGL(k_sort, dim3(1), dim3(64), 0, stream, clen, sort_ind, dlens);
  hipLaunchKernelGGL(k_mean, dim3(512), dim3(256), 0, stream, enc, sort_ind, mean_enc);
  hipLaunchKernelGGL(k_h0c0, dim3(32), dim3(256), 0, stream, mean_enc, Whi, bhi, Wci, bci,
                     hbuf0, cbuf0);
  hipLaunchKernelGGL(k_att1, dim3(784), dim3(256), 0, stream, enc, sort_ind, We, be, att1);

  float* hb[2] = {hbuf0, hbuf1};
  float* cb[2] = {cbuf0, cbuf1};
  for (int t = 0; t < TT; ++t) {
    const float* h_in = hb[t & 1];
    const float* c_in = cb[t & 1];
    float* h_out = hb[(t + 1) & 1];
    float* c_out = cb[(t + 1) & 1];
    hipLaunchKernelGGL(k_hproj, dim3(160), dim3(256), 0, stream, h_in, Wd, Wb, hpart);
    hipLaunchKernelGGL(k_hred, dim3(896), dim3(256), 0, stream,
                       hpart, bd, bb, emb, caps, sort_ind, h_in, att2, gateLin, xfull, t);
    hipLaunchKernelGGL(k_e, dim3(3136), dim3(256), 0, stream, att1, att2, Wf, bf, ebuf);
    hipLaunchKernelGGL(k_awe, dim3(128), dim3(256), 0, stream,
                       ebuf, enc, sort_ind, gateLin, dlens, xfull, alphas_out, t);
    hipLaunchKernelGGL(k_gates, dim3(192), dim3(256), 0, stream, xfull, Wih, Whh, gpart);
    hipLaunchKernelGGL(k_cell, dim3(128), dim3(256), 0, stream,
                       gpart, bih, bhh, c_in, h_out, c_out);
    hipLaunchKernelGGL(k_preds, dim3(160), dim3(256), 0, stream,
                       h_out, Wfc, bfc, dlens, preds_out, t);
  }
}

// Round 6
// 6022.508 us; speedup vs baseline: 2.6107x; 1.4337x over previous
//
#include <hip/hip_runtime.h>

#define BB 64
#define PP 196
#define EE 2048
#define LL 32
#define VV 10000
#define EMBD 512
#define DECD 512
#define ATTD 512
#define TT 31

#define FMA4(av, wv, A) {A[0]=fmaf((av),(wv).x,A[0]);A[1]=fmaf((av),(wv).y,A[1]);A[2]=fmaf((av),(wv).z,A[2]);A[3]=fmaf((av),(wv).w,A[3]);}

// ---------------- setup kernels ----------------

extern "C" __global__ void k_sort(const int* __restrict__ cap_len,
                                  int* __restrict__ sort_ind,
                                  int* __restrict__ dlens) {
  int i = threadIdx.x;
  if (i >= BB) return;
  int li = cap_len[i];
  int rank = 0;
  for (int j = 0; j < BB; ++j) {
    int lj = cap_len[j];
    rank += (lj > li) || (lj == li && j < i);   // stable argsort(-lens)
  }
  sort_ind[rank] = i;
  dlens[rank] = li - 1;
}

// mean over p: grid 512 = 64 b x 8 colchunks(256); threads 64 colquads x 4 pgroups
__global__ __launch_bounds__(256) void k_mean(const float* __restrict__ enc,
                                              const int* __restrict__ sort_ind,
                                              float* __restrict__ mean_enc) {
  int b = blockIdx.x >> 3, cch = blockIdx.x & 7;
  int ct = threadIdx.x & 63, pg = threadIdx.x >> 6;
  int col = (cch << 8) + (ct << 2);
  __shared__ float4 rbuf[4][64];
  const float* base = enc + (size_t)sort_ind[b] * PP * EE + col;
  float ax = 0.f, ay = 0.f, az = 0.f, aw = 0.f;
#pragma unroll 4
  for (int p = pg; p < PP; p += 4) {
    float4 v = *(const float4*)(base + (size_t)p * EE);
    ax += v.x; ay += v.y; az += v.z; aw += v.w;
  }
  rbuf[pg][ct] = make_float4(ax, ay, az, aw);
  __syncthreads();
  if (pg == 0) {
    float4 r0 = rbuf[0][ct], r1 = rbuf[1][ct], r2 = rbuf[2][ct], r3 = rbuf[3][ct];
    *(float4*)(mean_enc + b * EE + col) = make_float4(
        (r0.x + r1.x + r2.x + r3.x) * (1.0f / PP),
        (r0.y + r1.y + r2.y + r3.y) * (1.0f / PP),
        (r0.z + r1.z + r2.z + r3.z) * (1.0f / PP),
        (r0.w + r1.w + r2.w + r3.w) * (1.0f / PP));
  }
}

// h0 = mean_enc@Whi+bhi ; c0 = mean_enc@Wci+bci
__global__ __launch_bounds__(256) void k_h0c0(const float* __restrict__ mean_enc,
                                              const float* __restrict__ Whi,
                                              const float* __restrict__ bhi,
                                              const float* __restrict__ Wci,
                                              const float* __restrict__ bci,
                                              float* __restrict__ h0,
                                              float* __restrict__ c0) {
  int idx = blockIdx.x * 256 + threadIdx.x;      // 64*128 = 8192
  int b = idx >> 7, col = (idx & 127) * 4;
  const float* m = mean_enc + b * EE;
  float ah[4], ac[4];
  float4 bh = *(const float4*)(bhi + col);
  float4 bc = *(const float4*)(bci + col);
  ah[0]=bh.x; ah[1]=bh.y; ah[2]=bh.z; ah[3]=bh.w;
  ac[0]=bc.x; ac[1]=bc.y; ac[2]=bc.z; ac[3]=bc.w;
#pragma unroll 2
  for (int k = 0; k < EE; k += 4) {
    float4 mv = *(const float4*)(m + k);
    float4 wh0 = *(const float4*)(Whi + (size_t)(k+0)*DECD + col);
    float4 wh1 = *(const float4*)(Whi + (size_t)(k+1)*DECD + col);
    float4 wh2 = *(const float4*)(Whi + (size_t)(k+2)*DECD + col);
    float4 wh3 = *(const float4*)(Whi + (size_t)(k+3)*DECD + col);
    FMA4(mv.x, wh0, ah); FMA4(mv.y, wh1, ah); FMA4(mv.z, wh2, ah); FMA4(mv.w, wh3, ah);
    float4 wc0 = *(const float4*)(Wci + (size_t)(k+0)*DECD + col);
    float4 wc1 = *(const float4*)(Wci + (size_t)(k+1)*DECD + col);
    float4 wc2 = *(const float4*)(Wci + (size_t)(k+2)*DECD + col);
    float4 wc3 = *(const float4*)(Wci + (size_t)(k+3)*DECD + col);
    FMA4(mv.x, wc0, ac); FMA4(mv.y, wc1, ac); FMA4(mv.z, wc2, ac); FMA4(mv.w, wc3, ac);
  }
  *(float4*)(h0 + b * DECD + col) = make_float4(ah[0], ah[1], ah[2], ah[3]);
  *(float4*)(c0 + b * DECD + col) = make_float4(ac[0], ac[1], ac[2], ac[3]);
}

// att1 = enc[sorted]@We + be. 1568 blocks = 784 rowblk(16r) x 2 colblk(256c);
// thread 4r x 4c, register-rotated software pipeline (load k+4 before FMA k).
__global__ __launch_bounds__(256) void k_att1(const float* __restrict__ enc,
                                              const int* __restrict__ sort_ind,
                                              const float* __restrict__ We,
                                              const float* __restrict__ be,
                                              float* __restrict__ att1) {
  int rb = blockIdx.x >> 1;
  int cbk = blockIdx.x & 1;
  int ct = threadIdx.x & 63;
  int rg = threadIdx.x >> 6;
  int col = cbk * 256 + ct * 4;
  int row0 = rb * 16 + rg * 4;
  const float* ap[4];
#pragma unroll
  for (int i = 0; i < 4; ++i) {
    int row = row0 + i;
    int b = row / PP, p = row - b * PP;
    ap[i] = enc + ((size_t)sort_ind[b] * PP + p) * EE;
  }
  float acc[4][4];
  float4 bv = *(const float4*)(be + col);
#pragma unroll
  for (int i = 0; i < 4; ++i) { acc[i][0]=bv.x; acc[i][1]=bv.y; acc[i][2]=bv.z; acc[i][3]=bv.w; }
  const float* Wp = We + col;
  float4 w0 = *(const float4*)(Wp);
  float4 w1 = *(const float4*)(Wp + ATTD);
  float4 w2 = *(const float4*)(Wp + 2 * ATTD);
  float4 w3 = *(const float4*)(Wp + 3 * ATTD);
  float4 a0 = *(const float4*)(ap[0]);
  float4 a1 = *(const float4*)(ap[1]);
  float4 a2 = *(const float4*)(ap[2]);
  float4 a3 = *(const float4*)(ap[3]);
#pragma unroll 1
  for (int k = 0; k < EE - 4; k += 4) {
    const float* Wn = Wp + (size_t)(k + 4) * ATTD;
    float4 nw0 = *(const float4*)(Wn);
    float4 nw1 = *(const float4*)(Wn + ATTD);
    float4 nw2 = *(const float4*)(Wn + 2 * ATTD);
    float4 nw3 = *(const float4*)(Wn + 3 * ATTD);
    float4 na0 = *(const float4*)(ap[0] + k + 4);
    float4 na1 = *(const float4*)(ap[1] + k + 4);
    float4 na2 = *(const float4*)(ap[2] + k + 4);
    float4 na3 = *(const float4*)(ap[3] + k + 4);
    FMA4(a0.x, w0, acc[0]); FMA4(a0.y, w1, acc[0]); FMA4(a0.z, w2, acc[0]); FMA4(a0.w, w3, acc[0]);
    FMA4(a1.x, w0, acc[1]); FMA4(a1.y, w1, acc[1]); FMA4(a1.z, w2, acc[1]); FMA4(a1.w, w3, acc[1]);
    FMA4(a2.x, w0, acc[2]); FMA4(a2.y, w1, acc[2]); FMA4(a2.z, w2, acc[2]); FMA4(a2.w, w3, acc[2]);
    FMA4(a3.x, w0, acc[3]); FMA4(a3.y, w1, acc[3]); FMA4(a3.z, w2, acc[3]); FMA4(a3.w, w3, acc[3]);
    w0=nw0; w1=nw1; w2=nw2; w3=nw3;
    a0=na0; a1=na1; a2=na2; a3=na3;
  }
  FMA4(a0.x, w0, acc[0]); FMA4(a0.y, w1, acc[0]); FMA4(a0.z, w2, acc[0]); FMA4(a0.w, w3, acc[0]);
  FMA4(a1.x, w0, acc[1]); FMA4(a1.y, w1, acc[1]); FMA4(a1.z, w2, acc[1]); FMA4(a1.w, w3, acc[1]);
  FMA4(a2.x, w0, acc[2]); FMA4(a2.y, w1, acc[2]); FMA4(a2.z, w2, acc[2]); FMA4(a2.w, w3, acc[2]);
  FMA4(a3.x, w0, acc[3]); FMA4(a3.y, w1, acc[3]); FMA4(a3.z, w2, acc[3]); FMA4(a3.w, w3, acc[3]);
#pragma unroll
  for (int i = 0; i < 4; ++i)
    *(float4*)(att1 + (size_t)(row0 + i) * ATTD + col) =
        make_float4(acc[i][0], acc[i][1], acc[i][2], acc[i][3]);
}

// ---------------- per-step kernels ----------------

// hpart[sk][row][2560] of h@[Wd|Wb]. 320 blocks = 10cb x 8rb x 4sk; 2r4c; rotated.
__global__ __launch_bounds__(256) void k_hproj(const float* __restrict__ h_in,
                                               const float* __restrict__ Wd,
                                               const float* __restrict__ Wb,
                                               float* __restrict__ hpart) {
  int cb = blockIdx.x % 10;
  int rbk = (blockIdx.x / 10) & 7;
  int sk = blockIdx.x / 80;                      // 0..3, kr=128
  int ct = threadIdx.x & 63;
  int rg = threadIdx.x >> 6;
  int col = cb * 256 + ct * 4;
  int row0 = rbk * 8 + rg * 2;
  int k0 = sk * 128;
  const float* W;
  size_t ldw;
  if (col < ATTD) { W = Wd + (size_t)k0 * ATTD + col; ldw = ATTD; }
  else            { W = Wb + (size_t)k0 * EE + (col - ATTD); ldw = EE; }
  const float* hp = h_in + row0 * DECD + k0;
  float acc[2][4] = {{0,0,0,0},{0,0,0,0}};
  float4 w0 = *(const float4*)(W);
  float4 w1 = *(const float4*)(W + ldw);
  float4 w2 = *(const float4*)(W + 2 * ldw);
  float4 w3 = *(const float4*)(W + 3 * ldw);
  float4 a0 = *(const float4*)(hp);
  float4 a1 = *(const float4*)(hp + DECD);
#pragma unroll 1
  for (int k = 0; k < 124; k += 4) {
    const float* Wn = W + (size_t)(k + 4) * ldw;
    float4 nw0 = *(const float4*)(Wn);
    float4 nw1 = *(const float4*)(Wn + ldw);
    float4 nw2 = *(const float4*)(Wn + 2 * ldw);
    float4 nw3 = *(const float4*)(Wn + 3 * ldw);
    float4 na0 = *(const float4*)(hp + k + 4);
    float4 na1 = *(const float4*)(hp + DECD + k + 4);
    FMA4(a0.x, w0, acc[0]); FMA4(a0.y, w1, acc[0]); FMA4(a0.z, w2, acc[0]); FMA4(a0.w, w3, acc[0]);
    FMA4(a1.x, w0, acc[1]); FMA4(a1.y, w1, acc[1]); FMA4(a1.z, w2, acc[1]); FMA4(a1.w, w3, acc[1]);
    w0=nw0; w1=nw1; w2=nw2; w3=nw3; a0=na0; a1=na1;
  }
  FMA4(a0.x, w0, acc[0]); FMA4(a0.y, w1, acc[0]); FMA4(a0.z, w2, acc[0]); FMA4(a0.w, w3, acc[0]);
  FMA4(a1.x, w0, acc[1]); FMA4(a1.y, w1, acc[1]); FMA4(a1.z, w2, acc[1]); FMA4(a1.w, w3, acc[1]);
  float* out = hpart + (size_t)sk * (BB * 2560) + row0 * 2560 + col;
  *(float4*)(out)        = make_float4(acc[0][0], acc[0][1], acc[0][2], acc[0][3]);
  *(float4*)(out + 2560) = make_float4(acc[1][0], acc[1][1], acc[1][2], acc[1][3]);
}

// reduce hpart -> att2 (+bd) / gateLin (+bb); copy emb_t and h into xfull.
__global__ __launch_bounds__(256) void k_hred(const float* __restrict__ hpart,
                                              const float* __restrict__ bd,
                                              const float* __restrict__ bb,
                                              const float* __restrict__ emb,
                                              const int* __restrict__ caps,
                                              const int* __restrict__ sort_ind,
                                              const float* __restrict__ h_in,
                                              float* __restrict__ att2,
                                              float* __restrict__ gateLin,
                                              float* __restrict__ xfull,
                                              int t) {
  int idx = blockIdx.x * 256 + threadIdx.x;      // 64*2560 + 64*1024 = 229376
  if (idx < BB * 2560) {
    int b = idx / 2560, c = idx % 2560;
    float s = 0.f;
#pragma unroll
    for (int sk = 0; sk < 4; ++sk) s += hpart[(size_t)sk * (BB * 2560) + idx];
    if (c < ATTD) att2[b * ATTD + c] = s + bd[c];
    else gateLin[b * EE + (c - ATTD)] = s + bb[c - ATTD];
  } else {
    int cidx = idx - BB * 2560;
    int b = cidx >> 10, k = cidx & 1023;
    if (k < EMBD) {
      int cap = caps[sort_ind[b] * LL + t];
      xfull[b * 3072 + k] = emb[(size_t)cap * EMBD + k];
    } else {
      xfull[b * 3072 + 2560 + (k - EMBD)] = h_in[b * DECD + (k - EMBD)];
    }
  }
}

// e[b,p] = relu(att1[b,p,:] + att2[b,:]) . Wf + bf   (one wave per (b,p))
__global__ __launch_bounds__(256) void k_e(const float* __restrict__ att1,
                                           const float* __restrict__ att2,
                                           const float* __restrict__ Wf,
                                           const float* __restrict__ bf,
                                           float* __restrict__ e) {
  int wave = (blockIdx.x * 256 + threadIdx.x) >> 6;
  int lane = threadIdx.x & 63;
  int b = wave / PP, p = wave - b * PP;
  const float4* a1 = (const float4*)(att1 + (size_t)(b * PP + p) * ATTD);
  const float4* a2 = (const float4*)(att2 + b * ATTD);
  const float4* wf = (const float4*)Wf;
  float acc = 0.f;
#pragma unroll
  for (int r = 0; r < 2; ++r) {
    int k4 = lane + r * 64;
    float4 x = a1[k4], y = a2[k4], f = wf[k4];
    acc = fmaf(fmaxf(x.x + y.x, 0.f), f.x, acc);
    acc = fmaf(fmaxf(x.y + y.y, 0.f), f.y, acc);
    acc = fmaf(fmaxf(x.z + y.z, 0.f), f.z, acc);
    acc = fmaf(fmaxf(x.w + y.w, 0.f), f.w, acc);
  }
#pragma unroll
  for (int off = 32; off; off >>= 1) acc += __shfl_xor(acc, off);
  if (lane == 0) e[b * PP + p] = acc + bf[0];
}

// softmax + awe + gate. grid 512 = 64 b x 8 colchunks(256); 64 colquads x 4 pgroups.
__global__ __launch_bounds__(256) void k_awe(const float* __restrict__ e,
                                             const float* __restrict__ enc,
                                             const int* __restrict__ sort_ind,
                                             const float* __restrict__ gateLin,
                                             const int* __restrict__ dlens,
                                             float* __restrict__ xfull,
                                             float* __restrict__ alphas_out,
                                             int t) {
  int b = blockIdx.x >> 3, cch = blockIdx.x & 7;
  int tid = threadIdx.x;
  __shared__ float sa[PP];
  __shared__ float4 rbuf[4][64];
  float ev = 0.f;
  if (tid < PP) { ev = e[b * PP + tid]; sa[tid] = ev; }
  __syncthreads();
  float m = -1e30f;
  for (int p = 0; p < PP; ++p) m = fmaxf(m, sa[p]);
  __syncthreads();
  if (tid < PP) sa[tid] = expf(ev - m);
  __syncthreads();
  float s = 0.f;
  for (int p = 0; p < PP; ++p) s += sa[p];
  float inv = 1.0f / s;

  int ct = tid & 63, pg = tid >> 6;
  int col = (cch << 8) + (ct << 2);
  const float* base = enc + (size_t)sort_ind[b] * PP * EE + col;
  float ax = 0.f, ay = 0.f, az = 0.f, aw = 0.f;
#pragma unroll 4
  for (int p = pg; p < PP; p += 4) {
    float a = sa[p];
    float4 v = *(const float4*)(base + (size_t)p * EE);
    ax = fmaf(a, v.x, ax);
    ay = fmaf(a, v.y, ay);
    az = fmaf(a, v.z, az);
    aw = fmaf(a, v.w, aw);
  }
  rbuf[pg][ct] = make_float4(ax, ay, az, aw);
  __syncthreads();
  if (pg == 0) {
    float4 r0 = rbuf[0][ct], r1 = rbuf[1][ct], r2 = rbuf[2][ct], r3 = rbuf[3][ct];
    float sx = (r0.x + r1.x + r2.x + r3.x) * inv;
    float sy = (r0.y + r1.y + r2.y + r3.y) * inv;
    float sz = (r0.z + r1.z + r2.z + r3.z) * inv;
    float sw = (r0.w + r1.w + r2.w + r3.w) * inv;
    float4 gl = *(const float4*)(gateLin + b * EE + col);
    float gx = 1.f / (1.f + expf(-gl.x));
    float gy = 1.f / (1.f + expf(-gl.y));
    float gz = 1.f / (1.f + expf(-gl.z));
    float gw = 1.f / (1.f + expf(-gl.w));
    *(float4*)(xfull + b * 3072 + EMBD + col) =
        make_float4(sx * gx, sy * gy, sz * gz, sw * gw);
  }
  if (cch == 0 && tid < PP) {
    float msk = (t < dlens[b]) ? 1.f : 0.f;
    alphas_out[((size_t)b * TT + t) * PP + tid] = sa[tid] * inv * msk;
  }
}

// gpart[sk][row][2048]: xfull @ [Wih;Whh]. 384 blocks = 8cb x 8rb x 6sk; 2r4c; rotated.
__global__ __launch_bounds__(256) void k_gates(const float* __restrict__ xfull,
                                               const float* __restrict__ Wih,
                                               const float* __restrict__ Whh,
                                               float* __restrict__ gpart) {
  int cb = blockIdx.x & 7;
  int rbk = (blockIdx.x >> 3) & 7;
  int sk = blockIdx.x >> 6;                      // 0..5, kr=512
  int ct = threadIdx.x & 63;
  int rg = threadIdx.x >> 6;
  int col = cb * 256 + ct * 4;
  int row0 = rbk * 8 + rg * 2;
  const float* W = (sk < 5) ? (Wih + (size_t)(sk * 512) * EE + col) : (Whh + col);
  const float* xb = xfull + row0 * 3072 + (sk < 5 ? sk * 512 : 2560);
  float acc[2][4] = {{0,0,0,0},{0,0,0,0}};
  float4 w0 = *(const float4*)(W);
  float4 w1 = *(const float4*)(W + EE);
  float4 w2 = *(const float4*)(W + 2 * EE);
  float4 w3 = *(const float4*)(W + 3 * EE);
  float4 a0 = *(const float4*)(xb);
  float4 a1 = *(const float4*)(xb + 3072);
#pragma unroll 1
  for (int k = 0; k < 508; k += 4) {
    const float* Wn = W + (size_t)(k + 4) * EE;
    float4 nw0 = *(const float4*)(Wn);
    float4 nw1 = *(const float4*)(Wn + EE);
    float4 nw2 = *(const float4*)(Wn + 2 * EE);
    float4 nw3 = *(const float4*)(Wn + 3 * EE);
    float4 na0 = *(const float4*)(xb + k + 4);
    float4 na1 = *(const float4*)(xb + 3072 + k + 4);
    FMA4(a0.x, w0, acc[0]); FMA4(a0.y, w1, acc[0]); FMA4(a0.z, w2, acc[0]); FMA4(a0.w, w3, acc[0]);
    FMA4(a1.x, w0, acc[1]); FMA4(a1.y, w1, acc[1]); FMA4(a1.z, w2, acc[1]); FMA4(a1.w, w3, acc[1]);
    w0=nw0; w1=nw1; w2=nw2; w3=nw3; a0=na0; a1=na1;
  }
  FMA4(a0.x, w0, acc[0]); FMA4(a0.y, w1, acc[0]); FMA4(a0.z, w2, acc[0]); FMA4(a0.w, w3, acc[0]);
  FMA4(a1.x, w0, acc[1]); FMA4(a1.y, w1, acc[1]); FMA4(a1.z, w2, acc[1]); FMA4(a1.w, w3, acc[1]);
  float* out = gpart + (size_t)sk * (BB * EE) + row0 * EE + col;
  *(float4*)(out)      = make_float4(acc[0][0], acc[0][1], acc[0][2], acc[0][3]);
  *(float4*)(out + EE) = make_float4(acc[1][0], acc[1][1], acc[1][2], acc[1][3]);
}

__global__ __launch_bounds__(256) void k_cell(const float* __restrict__ gpart,
                                              const float* __restrict__ bih,
                                              const float* __restrict__ bhh,
                                              const float* __restrict__ c_in,
                                              float* __restrict__ h_out,
                                              float* __restrict__ c_out) {
  int idx = blockIdx.x * 256 + threadIdx.x;      // B*DEC = 32768
  int b = idx >> 9, j = idx & 511;
  float gi = bih[j] + bhh[j];
  float gf = bih[j + 512] + bhh[j + 512];
  float gg = bih[j + 1024] + bhh[j + 1024];
  float go = bih[j + 1536] + bhh[j + 1536];
#pragma unroll
  for (int s = 0; s < 6; ++s) {
    const float* gp = gpart + (size_t)s * (BB * EE) + b * EE;
    gi += gp[j];
    gf += gp[j + 512];
    gg += gp[j + 1024];
    go += gp[j + 1536];
  }
  float ig = 1.f / (1.f + expf(-gi));
  float fg = 1.f / (1.f + expf(-gf));
  float gt = tanhf(gg);
  float og = 1.f / (1.f + expf(-go));
  float cn = fg * c_in[idx] + ig * gt;
  float hn = og * tanhf(cn);
  h_out[idx] = hn;   // masked rows drift but outputs are mask-zeroed
  c_out[idx] = cn;
}

// preds = (h_out @ Wfc + bfc) * mask. 320 blocks = 40cb x 8rb; 2r4c; rotated.
__global__ __launch_bounds__(256) void k_preds(const float* __restrict__ hn,
                                               const float* __restrict__ Wfc,
                                               const float* __restrict__ bfc,
                                               const int* __restrict__ dlens,
                                               float* __restrict__ out,
                                               int t) {
  int cb = blockIdx.x % 40;
  int rbk = blockIdx.x / 40;
  int ct = threadIdx.x & 63;
  int rg = threadIdx.x >> 6;
  int col = cb * 256 + ct * 4;
  if (col >= VV) return;
  int row0 = rbk * 8 + rg * 2;
  const float* hp = hn + row0 * DECD;
  const float* W = Wfc + col;
  float acc[2][4];
  float4 bv = *(const float4*)(bfc + col);
  acc[0][0]=bv.x; acc[0][1]=bv.y; acc[0][2]=bv.z; acc[0][3]=bv.w;
  acc[1][0]=bv.x; acc[1][1]=bv.y; acc[1][2]=bv.z; acc[1][3]=bv.w;
  float4 w0 = *(const float4*)(W);
  float4 w1 = *(const float4*)(W + VV);
  float4 w2 = *(const float4*)(W + 2 * VV);
  float4 w3 = *(const float4*)(W + 3 * VV);
  float4 a0 = *(const float4*)(hp);
  float4 a1 = *(const float4*)(hp + DECD);
#pragma unroll 1
  for (int k = 0; k < DECD - 4; k += 4) {
    const float* Wn = W + (size_t)(k + 4) * VV;
    float4 nw0 = *(const float4*)(Wn);
    float4 nw1 = *(const float4*)(Wn + VV);
    float4 nw2 = *(const float4*)(Wn + 2 * VV);
    float4 nw3 = *(const float4*)(Wn + 3 * VV);
    float4 na0 = *(const float4*)(hp + k + 4);
    float4 na1 = *(const float4*)(hp + DECD + k + 4);
    FMA4(a0.x, w0, acc[0]); FMA4(a0.y, w1, acc[0]); FMA4(a0.z, w2, acc[0]); FMA4(a0.w, w3, acc[0]);
    FMA4(a1.x, w0, acc[1]); FMA4(a1.y, w1, acc[1]); FMA4(a1.z, w2, acc[1]); FMA4(a1.w, w3, acc[1]);
    w0=nw0; w1=nw1; w2=nw2; w3=nw3; a0=na0; a1=na1;
  }
  FMA4(a0.x, w0, acc[0]); FMA4(a0.y, w1, acc[0]); FMA4(a0.z, w2, acc[0]); FMA4(a0.w, w3, acc[0]);
  FMA4(a1.x, w0, acc[1]); FMA4(a1.y, w1, acc[1]); FMA4(a1.z, w2, acc[1]); FMA4(a1.w, w3, acc[1]);
#pragma unroll
  for (int i = 0; i < 2; ++i) {
    int b = row0 + i;
    float msk = (t < dlens[b]) ? 1.f : 0.f;
    *(float4*)(out + ((size_t)b * TT + t) * VV + col) =
        make_float4(acc[i][0] * msk, acc[i][1] * msk, acc[i][2] * msk, acc[i][3] * msk);
  }
}

// ---------------- launch ----------------

extern "C" void kernel_launch(void* const* d_in, const int* in_sizes, int n_in,
                              void* d_out, int out_size, void* d_ws, size_t ws_size,
                              hipStream_t stream) {
  const float* enc  = (const float*)d_in[0];
  const int*   caps = (const int*)d_in[1];
  const int*   clen = (const int*)d_in[2];
  const float* emb  = (const float*)d_in[3];
  const float* We   = (const float*)d_in[4];
  const float* be   = (const float*)d_in[5];
  const float* Wd   = (const float*)d_in[6];
  const float* bd   = (const float*)d_in[7];
  const float* Wf   = (const float*)d_in[8];
  const float* bf   = (const float*)d_in[9];
  const float* Wih  = (const float*)d_in[10];
  const float* bih  = (const float*)d_in[11];
  const float* Whh  = (const float*)d_in[12];
  const float* bhh  = (const float*)d_in[13];
  const float* Wb   = (const float*)d_in[14];
  const float* bb   = (const float*)d_in[15];
  const float* Whi  = (const float*)d_in[16];
  const float* bhi  = (const float*)d_in[17];
  const float* Wci  = (const float*)d_in[18];
  const float* bci  = (const float*)d_in[19];
  const float* Wfc  = (const float*)d_in[20];
  const float* bfc  = (const float*)d_in[21];

  // ws layout (floats), total 7,700,608 fl = 30.8 MB (same as proven R4/R5 layout)
  float* ws = (float*)d_ws;
  int* sort_ind  = (int*)ws;                     // 64
  int* dlens     = (int*)(ws + 64);              // 64
  float* hbuf0   = ws + 128;
  float* hbuf1   = ws + 32896;
  float* cbuf0   = ws + 65664;
  float* cbuf1   = ws + 98432;
  float* att2    = ws + 131200;
  float* gateLin = ws + 163968;
  float* xfull   = ws + 295040;
  float* spart   = ws + 491648;                  // 786432 shared scratch
  float* mean_enc = spart;                       //   setup (131072)
  float* hpart    = spart;                       //   4*64*2560 = 655360
  float* ebuf     = spart;                       //   12544
  float* gpart    = spart;                       //   6*64*2048 = 786432
  float* att1    = ws + 1278080;                 // 6422528
  float* preds_out  = (float*)d_out;
  float* alphas_out = preds_out + (size_t)BB * TT * VV;

  hipLaunchKernelGGL(k_sort, dim3(1), dim3(64), 0, stream, clen, sort_ind, dlens);
  hipLaunchKernelGGL(k_mean, dim3(512), dim3(256), 0, stream, enc, sort_ind, mean_enc);
  hipLaunchKernelGGL(k_h0c0, dim3(32), dim3(256), 0, stream, mean_enc, Whi, bhi, Wci, bci,
                     hbuf0, cbuf0);
  hipLaunchKernelGGL(k_att1, dim3(1568), dim3(256), 0, stream, enc, sort_ind, We, be, att1);

  float* hb[2] = {hbuf0, hbuf1};
  float* cb[2] = {cbuf0, cbuf1};
  for (int t = 0; t < TT; ++t) {
    const float* h_in = hb[t & 1];
    const float* c_in = cb[t & 1];
    float* h_out = hb[(t + 1) & 1];
    float* c_out = cb[(t + 1) & 1];
    hipLaunchKernelGGL(k_hproj, dim3(320), dim3(256), 0, stream, h_in, Wd, Wb, hpart);
    hipLaunchKernelGGL(k_hred, dim3(896), dim3(256), 0, stream,
                       hpart, bd, bb, emb, caps, sort_ind, h_in, att2, gateLin, xfull, t);
    hipLaunchKernelGGL(k_e, dim3(3136), dim3(256), 0, stream, att1, att2, Wf, bf, ebuf);
    hipLaunchKernelGGL(k_awe, dim3(512), dim3(256), 0, stream,
                       ebuf, enc, sort_ind, gateLin, dlens, xfull, alphas_out, t);
    hipLaunchKernelGGL(k_gates, dim3(384), dim3(256), 0, stream, xfull, Wih, Whh, gpart);
    hipLaunchKernelGGL(k_cell, dim3(128), dim3(256), 0, stream,
                       gpart, bih, bhh, c_in, h_out, c_out);
    hipLaunchKernelGGL(k_preds, dim3(320), dim3(256), 0, stream,
                       h_out, Wfc, bfc, dlens, preds_out, t);
  }
}